// Round 15
// baseline (246.271 us; speedup 1.0000x reference)
//
#include <hip/hip_runtime.h>
#include <math.h>

typedef short short8 __attribute__((ext_vector_type(8)));
typedef float f32x4  __attribute__((ext_vector_type(4)));
typedef unsigned short u16x4 __attribute__((ext_vector_type(4)));

__device__ __forceinline__ unsigned short f2b(float f) {
  union { float f; unsigned int u; } x; x.f = f;
  return (unsigned short)((x.u + 0x7FFFu + ((x.u >> 16) & 1u)) >> 16);
}
__device__ __forceinline__ float b2f_u(unsigned short u) {
  union { unsigned int u; float f; } x; x.u = ((unsigned int)u) << 16;
  return x.f;
}
__device__ __forceinline__ float sigm(float x) { return 1.f / (1.f + __expf(-x)); }
// tanh without libm branches; saturates to +/-1 without NaN.
__device__ __forceinline__ float tanh_fast(float x) {
  float t = __expf(2.f * x);
  return 1.f - 2.f / (t + 1.f);
}

// ---------------------------------------------------------------------------
// Prepack (unchanged from round 14).
// ---------------------------------------------------------------------------
__global__ __launch_bounds__(256) void prepack_kernel(
    const float* __restrict__ Wf,
    const float* __restrict__ Wc, const float* __restrict__ Wn,
    const float* __restrict__ as_c, const float* __restrict__ ad_c,
    const float* __restrict__ as_n, const float* __restrict__ ad_n,
    const float* __restrict__ Wproj,
    const float* __restrict__ Wih_f, const float* __restrict__ Wih_b,
    const float* __restrict__ Wout,
    const float* __restrict__ Whh_f, const float* __restrict__ Whh_b,
    unsigned short* __restrict__ fragB,
    unsigned short* __restrict__ fragWB,
    float* __restrict__ Wa,
    unsigned short* __restrict__ fragP,
    unsigned short* __restrict__ fragIH,
    unsigned short* __restrict__ fragO,
    unsigned short* __restrict__ fragHH)
{
  int e = blockIdx.x * 256 + threadIdx.x;
  unsigned short tmp[8];
  if (e < 4096) {
    int kb = e >> 9, tile = (e >> 6) & 7, lane = e & 63;
    int n = tile * 16 + (lane & 15);
    int kbase = kb * 32 + (lane >> 4) * 8;
#pragma unroll
    for (int j = 0; j < 8; j++) tmp[j] = f2b(Wf[(kbase + j) * 128 + n]);
    *(short8*)(fragB + e * 8) = *(short8*)tmp;
  } else if (e < 5120) {
    int i = e - 4096;
    int s = i >> 9, tile = (i >> 6) & 7, lane = i & 63;
    int c15 = lane & 15, quad = lane >> 4;
    int n = tile * 16 + c15;
    int h = n >> 5, o = n & 31;
    const float* W = s ? Wn : Wc;
#pragma unroll
    for (int j = 0; j < 8; j++) {
      int k = quad * 8 + j;
      tmp[j] = ((k >> 2) == h) ? f2b(W[h * 128 + (k & 3) * 32 + o])
                               : (unsigned short)0;
    }
    *(short8*)(fragWB + i * 8) = *(short8*)tmp;
  } else if (e < 5184) {
    int i = e - 5120;
    int s = i >> 5, d = (i >> 4) & 1, h = (i >> 2) & 3, f = i & 3;
    const float* W = s ? Wn : Wc;
    const float* a = s ? (d ? ad_n : as_n) : (d ? ad_c : as_c);
    float acc = 0.f;
#pragma unroll
    for (int o = 0; o < 32; o++) acc += W[h * 128 + f * 32 + o] * a[h * 32 + o];
    Wa[i] = acc;
  } else if (e < 6208) {
    int i = e - 5184;
    int kb = i >> 8, nt = (i >> 6) & 3, lane = i & 63;
    int c15 = lane & 15, quad = lane >> 4;
#pragma unroll
    for (int j = 0; j < 8; j++)
      tmp[j] = f2b(Wproj[(kb * 32 + quad * 8 + j) * 64 + nt * 16 + c15]);
    *(short8*)(fragP + i * 8) = *(short8*)tmp;
  } else if (e < 7744) {
    int i = e - 6208;
    int d = (i >= 768), r = i - d * 768;
    int kb = r / 384, nt = (r >> 6) % 6, lane = r & 63;
    int c15 = lane & 15, quad = lane >> 4;
    const float* W = d ? Wih_b : Wih_f;
#pragma unroll
    for (int j = 0; j < 8; j++)
      tmp[j] = f2b(W[(kb * 32 + quad * 8 + j) * 96 + nt * 16 + c15]);
    *(short8*)(fragIH + i * 8) = *(short8*)tmp;
  } else if (e < 9280) {
    int r = e - 7744;
    int kb = r >> 8, nt = (r >> 6) & 3, lane = r & 63;
    int c15 = lane & 15, quad = lane >> 4;
#pragma unroll
    for (int j = 0; j < 8; j++)
      tmp[j] = f2b(Wout[(kb * 32 + quad * 8 + j) * 64 + nt * 16 + c15]);
    *(short8*)(fragO + r * 8) = *(short8*)tmp;
  } else if (e < 10048) {
    int i = e - 9280;
    int d = i / 384, r = i - d * 384;
    int nt = r >> 6, lane = r & 63;
    int c15 = lane & 15, quad = lane >> 4;
    const float* W = d ? Whh_b : Whh_f;
#pragma unroll
    for (int j = 0; j < 8; j++)
      tmp[j] = f2b(W[(quad * 8 + j) * 96 + nt * 16 + c15]);
    *(short8*)(fragHH + i * 8) = *(short8*)tmp;
  }
}

// ---------------------------------------------------------------------------
// Kernel 1: GAT + fuse (unchanged from rounds 12/14 — 132 µs).
// ---------------------------------------------------------------------------
__global__ __launch_bounds__(256) void gat_fuse_kernel(
    const float* __restrict__ self_f, const float* __restrict__ nbr_f,
    const float* __restrict__ Wa,
    const unsigned short* __restrict__ fragWB,
    const unsigned short* __restrict__ fragB,
    const float* __restrict__ b_fuse,
    float* __restrict__ emb)
{
  const int tid = threadIdx.x;
  const int w = tid >> 6, lane = tid & 63, c15 = lane & 15, quad = lane >> 4;
  const int n0 = blockIdx.x * 2;
  const int ws = w & 1;
  const int wn = w >> 1;

  __shared__ __align__(16) float sxf[2][12][4];
  __shared__ float sWa[64];
  __shared__ float sed[2][2][4][12];
  __shared__ __align__(16) unsigned short sA[2][2][16][24];
  __shared__ __align__(16) unsigned short scatb[2][16][268];
  __shared__ float sbias[128];

  if (tid < 128) sbias[tid] = b_fuse[tid];
  if (tid < 64) sWa[tid] = Wa[tid];
  if (tid < 96) {
    int nd = tid / 48, f = tid - nd * 48;
    int nn = n0 + nd, b = nn / 5, slot = nn - b * 5;
    float v = (slot == 0) ? self_f[b * 48 + f]
                          : nbr_f[(b * 4 + slot - 1) * 48 + f];
    sxf[nd][f >> 2][f & 3] = v;
  }
  __syncthreads();

  float es_local = 0.f;
  if (tid < 192) {
    int g = tid / 96, r = tid - g * 96;
    int s = r / 48, r2 = r - s * 48;
    int h = r2 / 12, l = r2 - h * 12;
    float ed = 0.f;
#pragma unroll
    for (int f = 0; f < 4; f++) {
      float xv = sxf[g][l][f];
      es_local += xv * sWa[s * 32 + h * 4 + f];
      ed       += xv * sWa[s * 32 + 16 + h * 4 + f];
    }
    sed[g][s][h][l] = ed;
  }
  __syncthreads();

  if (tid < 192) {
    int g = tid / 96, r = tid - g * 96;
    int s = r / 48, r2 = r - s * 48;
    int h = r2 / 12, i = r2 - h * 12;
    int blk = i / 3;
    float ev[12];
    float m = -1e30f;
#pragma unroll
    for (int j = 0; j < 12; j++) {
      bool allowed = (s == 0) ? ((j / 3) == blk) : ((j / 3) != blk);
      float e = es_local + sed[g][s][h][j];
      e = e > 0.f ? e : 0.2f * e;
      if (!allowed) e = -1e30f;
      ev[j] = e;
      m = fmaxf(m, e);
    }
    float sum = 0.f;
#pragma unroll
    for (int j = 0; j < 12; j++) {
      float a = (ev[j] > -1e29f) ? __expf(ev[j] - m) : 0.f;
      ev[j] = a;
      sum += a;
    }
    float inv = 1.f / sum;
    float xa0 = 0.f, xa1 = 0.f, xa2 = 0.f, xa3 = 0.f;
#pragma unroll
    for (int j = 0; j < 12; j++) {
      float aj = ev[j] * inv;
      f32x4 xj = *(const f32x4*)&sxf[g][j][0];
      xa0 += aj * xj[0]; xa1 += aj * xj[1];
      xa2 += aj * xj[2]; xa3 += aj * xj[3];
    }
    u16x4 pk = { f2b(xa0), f2b(xa1), f2b(xa2), f2b(xa3) };
    *(u16x4*)&sA[g][s][i][h * 4] = pk;
  }
  __syncthreads();

  {
    const short8 z8 = {0,0,0,0,0,0,0,0};
    short8 a = z8;
    if (quad < 2) a = *(const short8*)&sA[wn][ws][c15][quad * 8];
#pragma unroll
    for (int tile = 0; tile < 8; tile++) {
      short8 bw = *(const short8*)(fragWB + ((ws * 8 + tile) * 64 + lane) * 8);
      f32x4 c = {0.f, 0.f, 0.f, 0.f};
      c = __builtin_amdgcn_mfma_f32_16x16x32_bf16(a, bw, c, 0, 0, 0);
      if (quad < 3) {
        int co = ws * 128 + tile * 16 + c15;
#pragma unroll
        for (int r = 0; r < 4; r++) {
          float v = c[r];
          v = v > 0.f ? v : (__expf(v) - 1.f);
          scatb[wn][quad * 4 + r][co] = f2b(v);
        }
      }
    }
  }
  __syncthreads();

  {
    f32x4 acc[2][2];
#pragma unroll
    for (int nd = 0; nd < 2; nd++)
#pragma unroll
      for (int tt = 0; tt < 2; tt++) acc[nd][tt] = (f32x4){0.f,0.f,0.f,0.f};
#pragma unroll
    for (int kb = 0; kb < 8; kb++) {
      short8 a0 = *(const short8*)&scatb[0][c15][kb * 32 + (quad << 3)];
      short8 a1 = *(const short8*)&scatb[1][c15][kb * 32 + (quad << 3)];
#pragma unroll
      for (int tt = 0; tt < 2; tt++) {
        short8 bw = *(const short8*)(fragB + ((kb * 8 + 2 * w + tt) * 64 + lane) * 8);
        acc[0][tt] = __builtin_amdgcn_mfma_f32_16x16x32_bf16(a0, bw, acc[0][tt], 0, 0, 0);
        acc[1][tt] = __builtin_amdgcn_mfma_f32_16x16x32_bf16(a1, bw, acc[1][tt], 0, 0, 0);
      }
    }
    float tot[2][2];
#pragma unroll
    for (int nd = 0; nd < 2; nd++) {
#pragma unroll
      for (int tt = 0; tt < 2; tt++) {
        float p = 0.f;
        if (quad < 3) {
          float bcol = sbias[w * 32 + tt * 16 + c15];
#pragma unroll
          for (int r = 0; r < 4; r++) {
            float v = acc[nd][tt][r] + bcol;
            v = v > 0.f ? v : (__expf(v) - 1.f);
            p += v;
          }
        }
        p += __shfl_xor(p, 16);
        p += __shfl_xor(p, 32);
        tot[nd][tt] = p;
      }
    }
    int ndw = quad >> 1, ttw = quad & 1;
    float val = ndw ? (ttw ? tot[1][1] : tot[1][0])
                    : (ttw ? tot[0][1] : tot[0][0]);
    emb[(n0 + ndw) * 128 + w * 32 + ttw * 16 + c15] = val * (1.f / 12.f);
  }
}

// ---------------------------------------------------------------------------
// Kernel 2: head — 4 samples per 128-thread block (2048 blocks), GRU loop is
// wave-local (dir = wave) so it runs with ZERO barriers. LDS ~21 KB.
// ---------------------------------------------------------------------------
__global__ __launch_bounds__(128) void head_kernel(
    const float* __restrict__ emb,
    const float* __restrict__ maskp, const float* __restrict__ dirsp,
    const float* __restrict__ W_proj, const float* __restrict__ b_proj,
    const unsigned short* __restrict__ fragP,
    const unsigned short* __restrict__ fragIH,
    const unsigned short* __restrict__ fragHH,
    const float* __restrict__ bih_f, const float* __restrict__ bhh_f,
    const float* __restrict__ bih_b, const float* __restrict__ bhh_b,
    const unsigned short* __restrict__ fragO,
    const float* __restrict__ b_out,
    float* __restrict__ out)
{
  const int b4 = blockIdx.x * 4;
  const int tid = threadIdx.x;             // 0..127
  const int w = tid >> 6, lane = tid & 63, c15 = lane & 15, quad = lane >> 4;

  // sXC: union of sX[16][72] (proj out, read by gi) and sCat[16][200]
  __shared__ __align__(16) unsigned short sXC[16][200];    // 6400 B
  __shared__ __align__(16) unsigned short sgi[2][16][96];  // 6144 B
  __shared__ float sH[2][4][32];                           // 1024 B
  __shared__ __align__(16) unsigned short sHb[2][16][32];  // 2048 B
  __shared__ float sgh[2][4][96];                          // 3072 B
  __shared__ float sPB[128];
  __shared__ float sBI[2][96], sBH[2][96], sBO[64];

  unsigned short (*sX)[72] = (unsigned short(*)[72])&sXC[0][0];

  if (tid < 64) { sPB[tid] = b_proj[tid]; sPB[64 + tid] = W_proj[128 * 64 + tid]; sBO[tid] = b_out[tid]; }
  if (tid < 96) { sBI[0][tid] = bih_f[tid]; sBI[1][tid] = bih_b[tid];
                  sBH[0][tid] = bhh_f[tid]; sBH[1][tid] = bhh_b[tid]; }
  {
    // sHb: 2*16*32 u16 = 512 dwords; sH: 256 f32
    unsigned int* hb = (unsigned int*)sHb;
#pragma unroll
    for (int i = 0; i < 4; i++) hb[tid + 128 * i] = 0u;
    float* hz = (float*)sH;
    hz[tid] = 0.f; hz[tid + 128] = 0.f;
  }
  __syncthreads();

  // ---- proj via MFMA: rows m = sample*4 + nbr (m = c15 for A) ----
  {
    const int sl = c15 >> 2, nbr = c15 & 3;
    const float* arow = emb + (((b4 + sl) * 5) + 1 + nbr) * 128;
    short8 a[4];
#pragma unroll
    for (int kb = 0; kb < 4; kb++) {
      const float* p = arow + kb * 32 + quad * 8;
      f32x4 v0 = *(const f32x4*)p;
      f32x4 v1 = *(const f32x4*)(p + 4);
      unsigned short tmp[8];
      tmp[0]=f2b(v0[0]); tmp[1]=f2b(v0[1]); tmp[2]=f2b(v0[2]); tmp[3]=f2b(v0[3]);
      tmp[4]=f2b(v1[0]); tmp[5]=f2b(v1[1]); tmp[6]=f2b(v1[2]); tmp[7]=f2b(v1[3]);
      a[kb] = *(short8*)tmp;
    }
    // C rows: m = quad*4 + r -> sample = quad, nbr/step = r
    float dirv[4], maskv[4];
#pragma unroll
    for (int r = 0; r < 4; r++) {
      dirv[r]  = dirsp[(b4 + quad) * 4 + r];
      maskv[r] = maskp[(b4 + quad) * 4 + r];
    }
#pragma unroll
    for (int tt = 0; tt < 2; tt++) {
      int nt = w * 2 + tt;
      f32x4 acc = {0.f,0.f,0.f,0.f};
#pragma unroll
      for (int kb = 0; kb < 4; kb++) {
        short8 bb = *(const short8*)(fragP + ((kb * 4 + nt) * 64 + lane) * 8);
        acc = __builtin_amdgcn_mfma_f32_16x16x32_bf16(a[kb], bb, acc, 0, 0, 0);
      }
      int col = nt * 16 + c15;
#pragma unroll
      for (int r = 0; r < 4; r++) {
        float v = acc[r] + dirv[r] * sPB[64 + col] + sPB[col];
        v = fmaxf(v, 0.f) * maskv[r];
        sX[quad * 4 + r][col] = f2b(v);
      }
    }
  }
  __syncthreads();

  // ---- gi via MFMA: wave w -> dir w; 6 N-tiles, K=64 ----
  {
    const int d = w;
    short8 a[2];
#pragma unroll
    for (int kb = 0; kb < 2; kb++)
      a[kb] = *(const short8*)&sX[c15][kb * 32 + quad * 8];
#pragma unroll
    for (int nt = 0; nt < 6; nt++) {
      f32x4 acc = {0.f,0.f,0.f,0.f};
#pragma unroll
      for (int kb = 0; kb < 2; kb++) {
        short8 bb = *(const short8*)(fragIH + ((d * 12 + kb * 6 + nt) * 64 + lane) * 8);
        acc = __builtin_amdgcn_mfma_f32_16x16x32_bf16(a[kb], bb, acc, 0, 0, 0);
      }
      int col = nt * 16 + c15;
      float bi = sBI[d][col];
#pragma unroll
      for (int r = 0; r < 4; r++)
        sgi[d][quad * 4 + r][col] = f2b(acc[r] + bi);   // row = sample*4+step
    }
  }
  __syncthreads();

  // ---- sequential GRU: fully wave-local (dir = wave) -> NO barriers ----
  {
    const int d = w;
    const int u = lane & 31;
    const int s0 = (lane >> 5) ? 1 : 0;     // handles samples s0, s0+2
    for (int step = 0; step < 4; step++) {
      // gh = H @ Whh_d : A rows = sample (0-3), K=32, N=96
      short8 a = *(const short8*)&sHb[d][c15][quad * 8];
#pragma unroll
      for (int nt = 0; nt < 6; nt++) {
        short8 bb = *(const short8*)(fragHH + ((d * 6 + nt) * 64 + lane) * 8);
        f32x4 c = {0.f,0.f,0.f,0.f};
        c = __builtin_amdgcn_mfma_f32_16x16x32_bf16(a, bb, c, 0, 0, 0);
        if (quad == 0) {
          int col = nt * 16 + c15;
#pragma unroll
          for (int r = 0; r < 4; r++) sgh[d][r][col] = c[r];
        }
      }
      // gate update (same wave wrote sgh/sHb; lgkmcnt orders LDS ops)
      const int k = d ? (3 - step) : step;
#pragma unroll
      for (int si = 0; si < 2; si++) {
        int s = s0 + si * 2;
        int row = s * 4 + k;
        float ghr = sgh[d][s][u]      + sBH[d][u];
        float ghz = sgh[d][s][32 + u] + sBH[d][32 + u];
        float ghn = sgh[d][s][64 + u] + sBH[d][64 + u];
        float r = sigm(b2f_u(sgi[d][row][u]) + ghr);
        float z = sigm(b2f_u(sgi[d][row][32 + u]) + ghz);
        float n = tanh_fast(b2f_u(sgi[d][row][64 + u]) + r * ghn);
        float h = (1.f - z) * n + z * sH[d][s][u];
        sH[d][s][u] = h;
        sHb[d][s][u] = f2b(h);
      }
    }
  }
  __syncthreads();

  // ---- build sCat rows 0-3 = [self_emb | h_f | h_b] (overwrites sX) ----
  for (int i = tid; i < 512; i += 128) {
    int s = i >> 7, cc = i & 127;
    sXC[s][cc] = f2b(emb[(b4 + s) * 5 * 128 + cc]);
  }
  for (int i = tid; i < 256; i += 128) {
    int s = i >> 6, j = i & 63;
    float hv = (j < 32) ? sH[0][s][j] : sH[1][s][j - 32];
    sXC[s][128 + j] = f2b(hv);
  }
  __syncthreads();

  // ---- out head via MFMA: wave w -> N-tiles {2w, 2w+1}; K=192 ----
  {
#pragma unroll
    for (int tt = 0; tt < 2; tt++) {
      int nt = w * 2 + tt;
      f32x4 acc = {0.f,0.f,0.f,0.f};
#pragma unroll
      for (int kb = 0; kb < 6; kb++) {
        short8 a = *(const short8*)&sXC[c15][kb * 32 + quad * 8];
        short8 bb = *(const short8*)(fragO + ((kb * 4 + nt) * 64 + lane) * 8);
        acc = __builtin_amdgcn_mfma_f32_16x16x32_bf16(a, bb, acc, 0, 0, 0);
      }
      if (quad == 0) {
        int col = nt * 16 + c15;
#pragma unroll
        for (int r = 0; r < 4; r++)
          out[(b4 + r) * 192 + 128 + col] = fmaxf(acc[r] + sBO[col], 0.f);
      }
    }
  }
  // ---- self_emb passthrough (f32 exact) ----
  for (int i = tid; i < 512; i += 128) {
    int s = i >> 7, cc = i & 127;
    out[(b4 + s) * 192 + cc] = emb[(b4 + s) * 5 * 128 + cc];
  }
}

// ---------------------------------------------------------------------------
extern "C" void kernel_launch(void* const* d_in, const int* in_sizes, int n_in,
                              void* d_out, int out_size, void* d_ws, size_t ws_size,
                              hipStream_t stream) {
  const float* self_f  = (const float*)d_in[0];
  const float* nbr_f   = (const float*)d_in[1];
  const float* maskp   = (const float*)d_in[2];
  const float* dirsp   = (const float*)d_in[3];
  const float* W_coop  = (const float*)d_in[4];
  const float* as_coop = (const float*)d_in[5];
  const float* ad_coop = (const float*)d_in[6];
  const float* W_conf  = (const float*)d_in[7];
  const float* as_conf = (const float*)d_in[8];
  const float* ad_conf = (const float*)d_in[9];
  const float* W_fuse  = (const float*)d_in[10];
  const float* b_fuse  = (const float*)d_in[11];
  const float* W_proj  = (const float*)d_in[12];
  const float* b_proj  = (const float*)d_in[13];
  const float* Wih_f   = (const float*)d_in[14];
  const float* Whh_f   = (const float*)d_in[15];
  const float* bih_f   = (const float*)d_in[16];
  const float* bhh_f   = (const float*)d_in[17];
  const float* Wih_b   = (const float*)d_in[18];
  const float* Whh_b   = (const float*)d_in[19];
  const float* bih_b   = (const float*)d_in[20];
  const float* bhh_b   = (const float*)d_in[21];
  const float* W_out   = (const float*)d_in[22];
  const float* b_out   = (const float*)d_in[23];

  const int B = in_sizes[0] / 48;   // 8192
  char* ws = (char*)d_ws;
  unsigned short* fragB  = (unsigned short*)(ws);            // 65536 B
  unsigned short* fragWB = (unsigned short*)(ws + 65536);    // 16384 B
  float*          Wa     = (float*)(ws + 81920);             // 256 B
  unsigned short* fragP  = (unsigned short*)(ws + 82176);    // 16384 B
  unsigned short* fragIH = (unsigned short*)(ws + 98560);    // 24576 B
  unsigned short* fragO  = (unsigned short*)(ws + 123136);   // 24576 B
  unsigned short* fragHH = (unsigned short*)(ws + 147712);   // 12288 B
  float*          emb    = (float*)(ws + 160000);            // B*5*128*4

  prepack_kernel<<<40, 256, 0, stream>>>(
      W_fuse, W_coop, W_conf, as_coop, ad_coop, as_conf, ad_conf,
      W_proj, Wih_f, Wih_b, W_out, Whh_f, Whh_b,
      fragB, fragWB, Wa, fragP, fragIH, fragO, fragHH);

  gat_fuse_kernel<<<B * 5 / 2, 256, 0, stream>>>(
      self_f, nbr_f, Wa, fragWB, fragB, b_fuse, emb);

  head_kernel<<<B / 4, 128, 0, stream>>>(
      emb, maskp, dirsp, W_proj, b_proj, fragP, fragIH, fragHH,
      bih_f, bhh_f, bih_b, bhh_b,
      fragO, b_out, (float*)d_out);
}

// Round 16
// 234.248 us; speedup vs baseline: 1.0513x; 1.0513x over previous
//
#include <hip/hip_runtime.h>
#include <hip/hip_bf16.h>
#include <math.h>

typedef short short8 __attribute__((ext_vector_type(8)));
typedef float f32x4  __attribute__((ext_vector_type(4)));
typedef unsigned short u16x4 __attribute__((ext_vector_type(4)));

__device__ __forceinline__ unsigned short f2b(float f) {
  union { float f; unsigned int u; } x; x.f = f;
  return (unsigned short)((x.u + 0x7FFFu + ((x.u >> 16) & 1u)) >> 16);
}
__device__ __forceinline__ float b2f_u(unsigned short u) {
  union { unsigned int u; float f; } x; x.u = ((unsigned int)u) << 16;
  return x.f;
}
// packed f32x2 -> bf16x2 (v_cvt_pk_bf16_f32, RTNE — bit-identical to f2b)
__device__ __forceinline__ unsigned int pkbf(float a, float b) {
  union { __hip_bfloat162 h; unsigned int u; } c;
  c.h = __float22bfloat162_rn(make_float2(a, b));
  return c.u;           // low 16 = a, high 16 = b
}
__device__ __forceinline__ float sigm(float x) { return 1.f / (1.f + __expf(-x)); }
__device__ __forceinline__ float eluf(float v) {
  return v > 0.f ? v : (__expf(v) - 1.f);
}

// ---------------------------------------------------------------------------
// Prepack (unchanged from round 14).
// ---------------------------------------------------------------------------
__global__ __launch_bounds__(256) void prepack_kernel(
    const float* __restrict__ Wf,
    const float* __restrict__ Wc, const float* __restrict__ Wn,
    const float* __restrict__ as_c, const float* __restrict__ ad_c,
    const float* __restrict__ as_n, const float* __restrict__ ad_n,
    const float* __restrict__ Wproj,
    const float* __restrict__ Wih_f, const float* __restrict__ Wih_b,
    const float* __restrict__ Wout,
    const float* __restrict__ Whh_f, const float* __restrict__ Whh_b,
    unsigned short* __restrict__ fragB,
    unsigned short* __restrict__ fragWB,
    float* __restrict__ Wa,
    unsigned short* __restrict__ fragP,
    unsigned short* __restrict__ fragIH,
    unsigned short* __restrict__ fragO,
    unsigned short* __restrict__ fragHH)
{
  int e = blockIdx.x * 256 + threadIdx.x;
  unsigned short tmp[8];
  if (e < 4096) {
    int kb = e >> 9, tile = (e >> 6) & 7, lane = e & 63;
    int n = tile * 16 + (lane & 15);
    int kbase = kb * 32 + (lane >> 4) * 8;
#pragma unroll
    for (int j = 0; j < 8; j++) tmp[j] = f2b(Wf[(kbase + j) * 128 + n]);
    *(short8*)(fragB + e * 8) = *(short8*)tmp;
  } else if (e < 5120) {
    int i = e - 4096;
    int s = i >> 9, tile = (i >> 6) & 7, lane = i & 63;
    int c15 = lane & 15, quad = lane >> 4;
    int n = tile * 16 + c15;
    int h = n >> 5, o = n & 31;
    const float* W = s ? Wn : Wc;
#pragma unroll
    for (int j = 0; j < 8; j++) {
      int k = quad * 8 + j;
      tmp[j] = ((k >> 2) == h) ? f2b(W[h * 128 + (k & 3) * 32 + o])
                               : (unsigned short)0;
    }
    *(short8*)(fragWB + i * 8) = *(short8*)tmp;
  } else if (e < 5184) {
    int i = e - 5120;
    int s = i >> 5, d = (i >> 4) & 1, h = (i >> 2) & 3, f = i & 3;
    const float* W = s ? Wn : Wc;
    const float* a = s ? (d ? ad_n : as_n) : (d ? ad_c : as_c);
    float acc = 0.f;
#pragma unroll
    for (int o = 0; o < 32; o++) acc += W[h * 128 + f * 32 + o] * a[h * 32 + o];
    Wa[i] = acc;
  } else if (e < 6208) {
    int i = e - 5184;
    int kb = i >> 8, nt = (i >> 6) & 3, lane = i & 63;
    int c15 = lane & 15, quad = lane >> 4;
#pragma unroll
    for (int j = 0; j < 8; j++)
      tmp[j] = f2b(Wproj[(kb * 32 + quad * 8 + j) * 64 + nt * 16 + c15]);
    *(short8*)(fragP + i * 8) = *(short8*)tmp;
  } else if (e < 7744) {
    int i = e - 6208;
    int d = (i >= 768), r = i - d * 768;
    int kb = r / 384, nt = (r >> 6) % 6, lane = r & 63;
    int c15 = lane & 15, quad = lane >> 4;
    const float* W = d ? Wih_b : Wih_f;
#pragma unroll
    for (int j = 0; j < 8; j++)
      tmp[j] = f2b(W[(kb * 32 + quad * 8 + j) * 96 + nt * 16 + c15]);
    *(short8*)(fragIH + i * 8) = *(short8*)tmp;
  } else if (e < 9280) {
    int r = e - 7744;
    int kb = r >> 8, nt = (r >> 6) & 3, lane = r & 63;
    int c15 = lane & 15, quad = lane >> 4;
#pragma unroll
    for (int j = 0; j < 8; j++)
      tmp[j] = f2b(Wout[(kb * 32 + quad * 8 + j) * 64 + nt * 16 + c15]);
    *(short8*)(fragO + r * 8) = *(short8*)tmp;
  } else if (e < 10048) {
    int i = e - 9280;
    int d = i / 384, r = i - d * 384;
    int nt = r >> 6, lane = r & 63;
    int c15 = lane & 15, quad = lane >> 4;
    const float* W = d ? Whh_b : Whh_f;
#pragma unroll
    for (int j = 0; j < 8; j++)
      tmp[j] = f2b(W[(quad * 8 + j) * 96 + nt * 16 + c15]);
    *(short8*)(fragHH + i * 8) = *(short8*)tmp;
  }
}

// ---------------------------------------------------------------------------
// Kernel 1: GAT + fuse. Changes vs r12/r14:
//  - phases 1/2 remapped stream-major (s = tid/96) so waves are stream-uniform
//  - masked softmax loops only over ALLOWED j (coop:3, conf:9) — bit-identical
//  - packed bf16 conversions (v_cvt_pk_bf16_f32) in phases 2/3
// ---------------------------------------------------------------------------
__global__ __launch_bounds__(256) void gat_fuse_kernel(
    const float* __restrict__ self_f, const float* __restrict__ nbr_f,
    const float* __restrict__ Wa,
    const unsigned short* __restrict__ fragWB,
    const unsigned short* __restrict__ fragB,
    const float* __restrict__ b_fuse,
    float* __restrict__ emb)
{
  const int tid = threadIdx.x;
  const int w = tid >> 6, lane = tid & 63, c15 = lane & 15, quad = lane >> 4;
  const int n0 = blockIdx.x * 2;
  const int ws = w & 1;
  const int wn = w >> 1;

  __shared__ __align__(16) float sxf[2][12][4];
  __shared__ float sWa[64];
  __shared__ float sed[2][2][4][12];
  __shared__ __align__(16) unsigned short sA[2][2][16][24];
  __shared__ __align__(16) unsigned short scatb[2][16][268];
  __shared__ float sbias[128];

  if (tid < 128) sbias[tid] = b_fuse[tid];
  if (tid < 64) sWa[tid] = Wa[tid];
  if (tid < 96) {
    int nd = tid / 48, f = tid - nd * 48;
    int nn = n0 + nd, b = nn / 5, slot = nn - b * 5;
    float v = (slot == 0) ? self_f[b * 48 + f]
                          : nbr_f[(b * 4 + slot - 1) * 48 + f];
    sxf[nd][f >> 2][f & 3] = v;
  }
  __syncthreads();

  // ---- phase 1: logits via Wa trick (stream-major mapping) ----
  float es_local = 0.f;
  if (tid < 192) {
    int s = tid / 96, r = tid - s * 96;
    int g = r / 48, r2 = r - g * 48;
    int h = r2 / 12, l = r2 - h * 12;
    float ed = 0.f;
#pragma unroll
    for (int f = 0; f < 4; f++) {
      float xv = sxf[g][l][f];
      es_local += xv * sWa[s * 32 + h * 4 + f];
      ed       += xv * sWa[s * 32 + 16 + h * 4 + f];
    }
    sed[g][s][h][l] = ed;
  }
  __syncthreads();

  // ---- phase 2: masked softmax + x_agg, allowed-j only (bit-identical) ----
  if (tid < 192) {
    int s = tid / 96, r = tid - s * 96;
    int g = r / 48, r2 = r - g * 48;
    int h = r2 / 12, i = r2 - h * 12;
    int blk = i / 3;
    float xa0 = 0.f, xa1 = 0.f, xa2 = 0.f, xa3 = 0.f;
    if (s == 0) {
      // coop: own 3-block only
      float ev[3];
      float m = -1e30f;
#pragma unroll
      for (int jj = 0; jj < 3; jj++) {
        float e = es_local + sed[g][0][h][blk * 3 + jj];
        e = e > 0.f ? e : 0.2f * e;
        ev[jj] = e;
        m = fmaxf(m, e);
      }
      float sum = 0.f;
#pragma unroll
      for (int jj = 0; jj < 3; jj++) { ev[jj] = __expf(ev[jj] - m); sum += ev[jj]; }
      float inv = 1.f / sum;
#pragma unroll
      for (int jj = 0; jj < 3; jj++) {
        float aj = ev[jj] * inv;
        f32x4 xj = *(const f32x4*)&sxf[g][blk * 3 + jj][0];
        xa0 += aj * xj[0]; xa1 += aj * xj[1];
        xa2 += aj * xj[2]; xa3 += aj * xj[3];
      }
    } else {
      // conf: the 9 lanes outside own block (ascending j preserved)
      float ev[9];
      float m = -1e30f;
#pragma unroll
      for (int jj = 0; jj < 9; jj++) {
        int j = jj < blk * 3 ? jj : jj + 3;
        float e = es_local + sed[g][1][h][j];
        e = e > 0.f ? e : 0.2f * e;
        ev[jj] = e;
        m = fmaxf(m, e);
      }
      float sum = 0.f;
#pragma unroll
      for (int jj = 0; jj < 9; jj++) { ev[jj] = __expf(ev[jj] - m); sum += ev[jj]; }
      float inv = 1.f / sum;
#pragma unroll
      for (int jj = 0; jj < 9; jj++) {
        int j = jj < blk * 3 ? jj : jj + 3;
        float aj = ev[jj] * inv;
        f32x4 xj = *(const f32x4*)&sxf[g][j][0];
        xa0 += aj * xj[0]; xa1 += aj * xj[1];
        xa2 += aj * xj[2]; xa3 += aj * xj[3];
      }
    }
    uint2 pk = make_uint2(pkbf(xa0, xa1), pkbf(xa2, xa3));
    *(uint2*)&sA[g][s][i][h * 4] = pk;    // row i, k = h*4..h*4+3 (8B aligned)
  }
  __syncthreads();

  // ---- phase 3: projection GEMM (block-diag W), ELU -> scatb ----
  {
    const short8 z8 = {0,0,0,0,0,0,0,0};
    short8 a = z8;
    if (quad < 2) a = *(const short8*)&sA[wn][ws][c15][quad * 8];
#pragma unroll
    for (int tile = 0; tile < 8; tile++) {
      short8 bw = *(const short8*)(fragWB + ((ws * 8 + tile) * 64 + lane) * 8);
      f32x4 c = {0.f, 0.f, 0.f, 0.f};
      c = __builtin_amdgcn_mfma_f32_16x16x32_bf16(a, bw, c, 0, 0, 0);
      if (quad < 3) {
        int co = ws * 128 + tile * 16 + c15;
        unsigned int p01 = pkbf(eluf(c[0]), eluf(c[1]));
        unsigned int p23 = pkbf(eluf(c[2]), eluf(c[3]));
        scatb[wn][quad * 4 + 0][co] = (unsigned short)(p01 & 0xffffu);
        scatb[wn][quad * 4 + 1][co] = (unsigned short)(p01 >> 16);
        scatb[wn][quad * 4 + 2][co] = (unsigned short)(p23 & 0xffffu);
        scatb[wn][quad * 4 + 3][co] = (unsigned short)(p23 >> 16);
      }
    }
  }
  __syncthreads();

  // ---- phase 4: fuse GEMM; wave w covers N-tiles {2w,2w+1}, both nodes ----
  {
    f32x4 acc[2][2];
#pragma unroll
    for (int nd = 0; nd < 2; nd++)
#pragma unroll
      for (int tt = 0; tt < 2; tt++) acc[nd][tt] = (f32x4){0.f,0.f,0.f,0.f};
#pragma unroll
    for (int kb = 0; kb < 8; kb++) {
      short8 a0 = *(const short8*)&scatb[0][c15][kb * 32 + (quad << 3)];
      short8 a1 = *(const short8*)&scatb[1][c15][kb * 32 + (quad << 3)];
#pragma unroll
      for (int tt = 0; tt < 2; tt++) {
        short8 bw = *(const short8*)(fragB + ((kb * 8 + 2 * w + tt) * 64 + lane) * 8);
        acc[0][tt] = __builtin_amdgcn_mfma_f32_16x16x32_bf16(a0, bw, acc[0][tt], 0, 0, 0);
        acc[1][tt] = __builtin_amdgcn_mfma_f32_16x16x32_bf16(a1, bw, acc[1][tt], 0, 0, 0);
      }
    }
    float tot[2][2];
#pragma unroll
    for (int nd = 0; nd < 2; nd++) {
#pragma unroll
      for (int tt = 0; tt < 2; tt++) {
        float p = 0.f;
        if (quad < 3) {
          float bcol = sbias[w * 32 + tt * 16 + c15];
#pragma unroll
          for (int r = 0; r < 4; r++) p += eluf(acc[nd][tt][r] + bcol);
        }
        p += __shfl_xor(p, 16);
        p += __shfl_xor(p, 32);
        tot[nd][tt] = p;
      }
    }
    int ndw = quad >> 1, ttw = quad & 1;
    float val = ndw ? (ttw ? tot[1][1] : tot[1][0])
                    : (ttw ? tot[0][1] : tot[0][0]);
    emb[(n0 + ndw) * 128 + w * 32 + ttw * 16 + c15] = val * (1.f / 12.f);
  }
}

// ---------------------------------------------------------------------------
// Kernel 2: head — ROUND-14 VERSION (best measured total; r15 variant reverted).
// ---------------------------------------------------------------------------
__global__ __launch_bounds__(256) void head_kernel(
    const float* __restrict__ emb,
    const float* __restrict__ maskp, const float* __restrict__ dirsp,
    const float* __restrict__ W_proj, const float* __restrict__ b_proj,
    const unsigned short* __restrict__ fragP,
    const unsigned short* __restrict__ fragIH,
    const unsigned short* __restrict__ fragHH,
    const float* __restrict__ bih_f, const float* __restrict__ bhh_f,
    const float* __restrict__ bih_b, const float* __restrict__ bhh_b,
    const unsigned short* __restrict__ fragO,
    const float* __restrict__ b_out,
    float* __restrict__ out)
{
  const int b8 = blockIdx.x * 8;
  const int tid = threadIdx.x;
  const int w = tid >> 6, lane = tid & 63, c15 = lane & 15, quad = lane >> 4;

  __shared__ __align__(16) unsigned short sX[32][72];
  __shared__ __align__(16) unsigned short sgi[2][32][96];
  __shared__ float sH[2][8][32];
  __shared__ __align__(16) unsigned short sHb[2][16][32];
  __shared__ float sgh[2][8][96];
  __shared__ __align__(16) unsigned short sCat[16][200];
  __shared__ float sPB[128];
  __shared__ float sBI[2][96], sBH[2][96], sBO[64];

  if (tid < 64) { sPB[tid] = b_proj[tid]; sPB[64 + tid] = W_proj[128 * 64 + tid]; sBO[tid] = b_out[tid]; }
  if (tid < 96) { sBI[0][tid] = bih_f[tid]; sBI[1][tid] = bih_b[tid];
                  sBH[0][tid] = bhh_f[tid]; sBH[1][tid] = bhh_b[tid]; }
  {
    unsigned int* hb = (unsigned int*)sHb;
    hb[tid] = 0u; hb[tid + 256] = 0u;
    float* hz = (float*)sH;
    for (int i = tid; i < 512; i += 256) hz[i] = 0.f;
  }
  __syncthreads();

  // ---- proj via MFMA ----
  {
    const int mt = w >> 1;
    const int nt0 = (w & 1) * 2;
    const int sloc = mt * 4 + (c15 >> 2);
    const int nbr  = c15 & 3;
    const float* arow = emb + (((b8 + sloc) * 5) + 1 + nbr) * 128;
    short8 a[4];
#pragma unroll
    for (int kb = 0; kb < 4; kb++) {
      const float* p = arow + kb * 32 + quad * 8;
      f32x4 v0 = *(const f32x4*)p;
      f32x4 v1 = *(const f32x4*)(p + 4);
      unsigned short tmp[8];
      tmp[0]=f2b(v0[0]); tmp[1]=f2b(v0[1]); tmp[2]=f2b(v0[2]); tmp[3]=f2b(v0[3]);
      tmp[4]=f2b(v1[0]); tmp[5]=f2b(v1[1]); tmp[6]=f2b(v1[2]); tmp[7]=f2b(v1[3]);
      a[kb] = *(short8*)tmp;
    }
    f32x4 acc0 = {0.f,0.f,0.f,0.f}, acc1 = acc0;
#pragma unroll
    for (int kb = 0; kb < 4; kb++) {
      short8 b0 = *(const short8*)(fragP + ((kb * 4 + nt0    ) * 64 + lane) * 8);
      short8 b1 = *(const short8*)(fragP + ((kb * 4 + nt0 + 1) * 64 + lane) * 8);
      acc0 = __builtin_amdgcn_mfma_f32_16x16x32_bf16(a[kb], b0, acc0, 0, 0, 0);
      acc1 = __builtin_amdgcn_mfma_f32_16x16x32_bf16(a[kb], b1, acc1, 0, 0, 0);
    }
    const int sE = mt * 4 + quad;
    float dirv[4], maskv[4];
#pragma unroll
    for (int r = 0; r < 4; r++) {
      dirv[r]  = dirsp[(b8 + sE) * 4 + r];
      maskv[r] = maskp[(b8 + sE) * 4 + r];
    }
#pragma unroll
    for (int tt = 0; tt < 2; tt++) {
      f32x4 c = tt ? acc1 : acc0;
      int col = (nt0 + tt) * 16 + c15;
#pragma unroll
      for (int r = 0; r < 4; r++) {
        float v = c[r] + dirv[r] * sPB[64 + col] + sPB[col];
        v = fmaxf(v, 0.f) * maskv[r];
        sX[mt * 16 + quad * 4 + r][col] = f2b(v);
      }
    }
  }
  __syncthreads();

  // ---- gi via MFMA ----
  {
    const int mt = w >> 1;
    const int ntb = (w & 1) * 3;
    short8 a[2];
#pragma unroll
    for (int kb = 0; kb < 2; kb++)
      a[kb] = *(const short8*)&sX[mt * 16 + c15][kb * 32 + quad * 8];
#pragma unroll
    for (int d = 0; d < 2; d++) {
#pragma unroll
      for (int t2 = 0; t2 < 3; t2++) {
        int nt = ntb + t2;
        f32x4 acc = {0.f,0.f,0.f,0.f};
#pragma unroll
        for (int kb = 0; kb < 2; kb++) {
          short8 bb = *(const short8*)(fragIH + ((d * 12 + kb * 6 + nt) * 64 + lane) * 8);
          acc = __builtin_amdgcn_mfma_f32_16x16x32_bf16(a[kb], bb, acc, 0, 0, 0);
        }
        int col = nt * 16 + c15;
        float bi = sBI[d][col];
#pragma unroll
        for (int r = 0; r < 4; r++)
          sgi[d][mt * 16 + quad * 4 + r][col] = f2b(acc[r] + bi);
      }
    }
  }
  __syncthreads();

  // ---- sequential GRU via MFMA: gh = H @ Whh per step/dir ----
  {
    const int d_mfma = w >> 1;
    const int nt0 = (w & 1) * 3;
    const int u = tid & 31;
    const int s = (tid >> 5) & 7;
    const int grow = s * 4;
    for (int step = 0; step < 4; step++) {
      short8 a = *(const short8*)&sHb[d_mfma][c15][quad * 8];
#pragma unroll
      for (int t2 = 0; t2 < 3; t2++) {
        short8 bb = *(const short8*)(fragHH + ((d_mfma * 6 + nt0 + t2) * 64 + lane) * 8);
        f32x4 c = {0.f,0.f,0.f,0.f};
        c = __builtin_amdgcn_mfma_f32_16x16x32_bf16(a, bb, c, 0, 0, 0);
        if (quad < 2) {
          int col = (nt0 + t2) * 16 + c15;
#pragma unroll
          for (int r = 0; r < 4; r++)
            sgh[d_mfma][quad * 4 + r][col] = c[r];
        }
      }
      __syncthreads();
#pragma unroll
      for (int d = 0; d < 2; d++) {
        int k = d ? (3 - step) : step;
        int row = grow + k;
        float ghr = sgh[d][s][u]      + sBH[d][u];
        float ghz = sgh[d][s][32 + u] + sBH[d][32 + u];
        float ghn = sgh[d][s][64 + u] + sBH[d][64 + u];
        float r = sigm(b2f_u(sgi[d][row][u]) + ghr);
        float z = sigm(b2f_u(sgi[d][row][32 + u]) + ghz);
        float n = tanhf(b2f_u(sgi[d][row][64 + u]) + r * ghn);
        float h = (1.f - z) * n + z * sH[d][s][u];
        sH[d][s][u] = h;
        sHb[d][s][u] = f2b(h);
      }
      __syncthreads();
    }
  }

  // ---- build sCat = [self_emb | h_f | h_b] ----
  for (int i = tid; i < 8 * 128; i += 256) {
    int s = i >> 7, cc = i & 127;
    sCat[s][cc] = f2b(emb[(b8 + s) * 5 * 128 + cc]);
  }
  for (int i = tid; i < 512; i += 256) {
    int s = i >> 6, j = i & 63;
    float hv = (j < 32) ? sH[0][s][j] : sH[1][s][j - 32];
    sCat[s][128 + j] = f2b(hv);
  }
  __syncthreads();

  // ---- out head via MFMA ----
  {
    const int nt = w;
    f32x4 acc = {0.f,0.f,0.f,0.f};
#pragma unroll
    for (int kb = 0; kb < 6; kb++) {
      short8 a = *(const short8*)&sCat[c15][kb * 32 + quad * 8];
      short8 bb = *(const short8*)(fragO + ((kb * 4 + nt) * 64 + lane) * 8);
      acc = __builtin_amdgcn_mfma_f32_16x16x32_bf16(a, bb, acc, 0, 0, 0);
    }
    if (quad < 2) {
      int col = nt * 16 + c15;
#pragma unroll
      for (int r = 0; r < 4; r++) {
        int m = quad * 4 + r;
        out[(b8 + m) * 192 + 128 + col] = fmaxf(acc[r] + sBO[col], 0.f);
      }
    }
  }
  for (int i = tid; i < 8 * 128; i += 256) {
    int s = i >> 7, cc = i & 127;
    out[(b8 + s) * 192 + cc] = emb[(b8 + s) * 5 * 128 + cc];
  }
}

// ---------------------------------------------------------------------------
extern "C" void kernel_launch(void* const* d_in, const int* in_sizes, int n_in,
                              void* d_out, int out_size, void* d_ws, size_t ws_size,
                              hipStream_t stream) {
  const float* self_f  = (const float*)d_in[0];
  const float* nbr_f   = (const float*)d_in[1];
  const float* maskp   = (const float*)d_in[2];
  const float* dirsp   = (const float*)d_in[3];
  const float* W_coop  = (const float*)d_in[4];
  const float* as_coop = (const float*)d_in[5];
  const float* ad_coop = (const float*)d_in[6];
  const float* W_conf  = (const float*)d_in[7];
  const float* as_conf = (const float*)d_in[8];
  const float* ad_conf = (const float*)d_in[9];
  const float* W_fuse  = (const float*)d_in[10];
  const float* b_fuse  = (const float*)d_in[11];
  const float* W_proj  = (const float*)d_in[12];
  const float* b_proj  = (const float*)d_in[13];
  const float* Wih_f   = (const float*)d_in[14];
  const float* Whh_f   = (const float*)d_in[15];
  const float* bih_f   = (const float*)d_in[16];
  const float* bhh_f   = (const float*)d_in[17];
  const float* Wih_b   = (const float*)d_in[18];
  const float* Whh_b   = (const float*)d_in[19];
  const float* bih_b   = (const float*)d_in[20];
  const float* bhh_b   = (const float*)d_in[21];
  const float* W_out   = (const float*)d_in[22];
  const float* b_out   = (const float*)d_in[23];

  const int B = in_sizes[0] / 48;   // 8192
  char* ws = (char*)d_ws;
  unsigned short* fragB  = (unsigned short*)(ws);            // 65536 B
  unsigned short* fragWB = (unsigned short*)(ws + 65536);    // 16384 B
  float*          Wa     = (float*)(ws + 81920);             // 256 B
  unsigned short* fragP  = (unsigned short*)(ws + 82176);    // 16384 B
  unsigned short* fragIH = (unsigned short*)(ws + 98560);    // 24576 B
  unsigned short* fragO  = (unsigned short*)(ws + 123136);   // 24576 B
  unsigned short* fragHH = (unsigned short*)(ws + 147712);   // 12288 B
  float*          emb    = (float*)(ws + 160000);            // B*5*128*4

  prepack_kernel<<<40, 256, 0, stream>>>(
      W_fuse, W_coop, W_conf, as_coop, ad_coop, as_conf, ad_conf,
      W_proj, Wih_f, Wih_b, W_out, Whh_f, Whh_b,
      fragB, fragWB, Wa, fragP, fragIH, fragO, fragHH);

  gat_fuse_kernel<<<B * 5 / 2, 256, 0, stream>>>(
      self_f, nbr_f, Wa, fragWB, fragB, b_fuse, emb);

  head_kernel<<<B / 8, 256, 0, stream>>>(
      emb, maskp, dirsp, W_proj, b_proj, fragP, fragIH, fragHH,
      bih_f, bhh_f, bih_b, bhh_b,
      fragO, b_out, (float*)d_out);
}

// Round 17
// 224.583 us; speedup vs baseline: 1.0966x; 1.0430x over previous
//
#include <hip/hip_runtime.h>
#include <hip/hip_bf16.h>
#include <math.h>

typedef short short8 __attribute__((ext_vector_type(8)));
typedef float f32x4  __attribute__((ext_vector_type(4)));
typedef unsigned short u16x4 __attribute__((ext_vector_type(4)));

__device__ __forceinline__ unsigned short f2b(float f) {
  union { float f; unsigned int u; } x; x.f = f;
  return (unsigned short)((x.u + 0x7FFFu + ((x.u >> 16) & 1u)) >> 16);
}
__device__ __forceinline__ float b2f_u(unsigned short u) {
  union { unsigned int u; float f; } x; x.u = ((unsigned int)u) << 16;
  return x.f;
}
// packed f32x2 -> bf16x2 (v_cvt_pk_bf16_f32, RTNE)
__device__ __forceinline__ unsigned int pkbf(float a, float b) {
  union { __hip_bfloat162 h; unsigned int u; } c;
  c.h = __float22bfloat162_rn(make_float2(a, b));
  return c.u;
}
__device__ __forceinline__ float sigm(float x) { return 1.f / (1.f + __expf(-x)); }
__device__ __forceinline__ float eluf(float v) {
  return v > 0.f ? v : (__expf(v) - 1.f);
}

// ---------------------------------------------------------------------------
// Prepack (unchanged).
// ---------------------------------------------------------------------------
__global__ __launch_bounds__(256) void prepack_kernel(
    const float* __restrict__ Wf,
    const float* __restrict__ Wc, const float* __restrict__ Wn,
    const float* __restrict__ as_c, const float* __restrict__ ad_c,
    const float* __restrict__ as_n, const float* __restrict__ ad_n,
    const float* __restrict__ Wproj,
    const float* __restrict__ Wih_f, const float* __restrict__ Wih_b,
    const float* __restrict__ Wout,
    const float* __restrict__ Whh_f, const float* __restrict__ Whh_b,
    unsigned short* __restrict__ fragB,
    unsigned short* __restrict__ fragWB,
    float* __restrict__ Wa,
    unsigned short* __restrict__ fragP,
    unsigned short* __restrict__ fragIH,
    unsigned short* __restrict__ fragO,
    unsigned short* __restrict__ fragHH)
{
  int e = blockIdx.x * 256 + threadIdx.x;
  unsigned short tmp[8];
  if (e < 4096) {
    int kb = e >> 9, tile = (e >> 6) & 7, lane = e & 63;
    int n = tile * 16 + (lane & 15);
    int kbase = kb * 32 + (lane >> 4) * 8;
#pragma unroll
    for (int j = 0; j < 8; j++) tmp[j] = f2b(Wf[(kbase + j) * 128 + n]);
    *(short8*)(fragB + e * 8) = *(short8*)tmp;
  } else if (e < 5120) {
    int i = e - 4096;
    int s = i >> 9, tile = (i >> 6) & 7, lane = i & 63;
    int c15 = lane & 15, quad = lane >> 4;
    int n = tile * 16 + c15;
    int h = n >> 5, o = n & 31;
    const float* W = s ? Wn : Wc;
#pragma unroll
    for (int j = 0; j < 8; j++) {
      int k = quad * 8 + j;
      tmp[j] = ((k >> 2) == h) ? f2b(W[h * 128 + (k & 3) * 32 + o])
                               : (unsigned short)0;
    }
    *(short8*)(fragWB + i * 8) = *(short8*)tmp;
  } else if (e < 5184) {
    int i = e - 5120;
    int s = i >> 5, d = (i >> 4) & 1, h = (i >> 2) & 3, f = i & 3;
    const float* W = s ? Wn : Wc;
    const float* a = s ? (d ? ad_n : as_n) : (d ? ad_c : as_c);
    float acc = 0.f;
#pragma unroll
    for (int o = 0; o < 32; o++) acc += W[h * 128 + f * 32 + o] * a[h * 32 + o];
    Wa[i] = acc;
  } else if (e < 6208) {
    int i = e - 5184;
    int kb = i >> 8, nt = (i >> 6) & 3, lane = i & 63;
    int c15 = lane & 15, quad = lane >> 4;
#pragma unroll
    for (int j = 0; j < 8; j++)
      tmp[j] = f2b(Wproj[(kb * 32 + quad * 8 + j) * 64 + nt * 16 + c15]);
    *(short8*)(fragP + i * 8) = *(short8*)tmp;
  } else if (e < 7744) {
    int i = e - 6208;
    int d = (i >= 768), r = i - d * 768;
    int kb = r / 384, nt = (r >> 6) % 6, lane = r & 63;
    int c15 = lane & 15, quad = lane >> 4;
    const float* W = d ? Wih_b : Wih_f;
#pragma unroll
    for (int j = 0; j < 8; j++)
      tmp[j] = f2b(W[(kb * 32 + quad * 8 + j) * 96 + nt * 16 + c15]);
    *(short8*)(fragIH + i * 8) = *(short8*)tmp;
  } else if (e < 9280) {
    int r = e - 7744;
    int kb = r >> 8, nt = (r >> 6) & 3, lane = r & 63;
    int c15 = lane & 15, quad = lane >> 4;
#pragma unroll
    for (int j = 0; j < 8; j++)
      tmp[j] = f2b(Wout[(kb * 32 + quad * 8 + j) * 64 + nt * 16 + c15]);
    *(short8*)(fragO + r * 8) = *(short8*)tmp;
  } else if (e < 10048) {
    int i = e - 9280;
    int d = i / 384, r = i - d * 384;
    int nt = r >> 6, lane = r & 63;
    int c15 = lane & 15, quad = lane >> 4;
    const float* W = d ? Whh_b : Whh_f;
#pragma unroll
    for (int j = 0; j < 8; j++)
      tmp[j] = f2b(W[(quad * 8 + j) * 96 + nt * 16 + c15]);
    *(short8*)(fragHH + i * 8) = *(short8*)tmp;
  }
}

// ---------------------------------------------------------------------------
// Kernel 1: GAT + fuse — 2 barriers total. Wave w owns quadrant
// (g = w&1 node, s = w>>1 stream) through logits->softmax->x_agg->proj-GEMM
// (wave-local LDS, lgkmcnt-ordered). Barriers: after stage, before fuse.
// ---------------------------------------------------------------------------
__global__ __launch_bounds__(256) void gat_fuse_kernel(
    const float* __restrict__ self_f, const float* __restrict__ nbr_f,
    const float* __restrict__ Wa,
    const unsigned short* __restrict__ fragWB,
    const unsigned short* __restrict__ fragB,
    const float* __restrict__ b_fuse,
    float* __restrict__ emb)
{
  const int tid = threadIdx.x;
  const int w = tid >> 6, lane = tid & 63, c15 = lane & 15, quad = lane >> 4;
  const int n0 = blockIdx.x * 2;

  __shared__ __align__(16) float sxf[2][12][4];
  __shared__ float sWa[64];
  __shared__ float sed[2][2][4][12];
  __shared__ __align__(16) unsigned short sA[2][2][16][24];
  __shared__ __align__(16) unsigned short scatb[2][16][268];
  __shared__ float sbias[128];

  if (tid < 128) sbias[tid] = b_fuse[tid];
  if (tid < 64) sWa[tid] = Wa[tid];
  if (tid < 96) {
    int nd = tid / 48, f = tid - nd * 48;
    int nn = n0 + nd, b = nn / 5, slot = nn - b * 5;
    float v = (slot == 0) ? self_f[b * 48 + f]
                          : nbr_f[(b * 4 + slot - 1) * 48 + f];
    sxf[nd][f >> 2][f & 3] = v;
  }
  __syncthreads();                             // barrier 1 (stage)

  // ---- phases 1+2 (wave-local): wave w -> g = w&1, s = w>>1; lanes 0-47 ----
  const int g_q = w & 1, s_q = w >> 1;
  if (lane < 48) {
    int h = lane / 12, i = lane - h * 12;
    // logits (own row i)
    float es = 0.f, ed = 0.f;
#pragma unroll
    for (int f = 0; f < 4; f++) {
      float xv = sxf[g_q][i][f];
      es += xv * sWa[s_q * 32 + h * 4 + f];
      ed += xv * sWa[s_q * 32 + 16 + h * 4 + f];
    }
    sed[g_q][s_q][h][i] = ed;
    // softmax over allowed j only (same wave wrote sed; lgkmcnt orders)
    int blk = i / 3;
    float xa0 = 0.f, xa1 = 0.f, xa2 = 0.f, xa3 = 0.f;
    if (s_q == 0) {
      float ev[3];
      float m = -1e30f;
#pragma unroll
      for (int jj = 0; jj < 3; jj++) {
        float e = es + sed[g_q][0][h][blk * 3 + jj];
        e = e > 0.f ? e : 0.2f * e;
        ev[jj] = e;
        m = fmaxf(m, e);
      }
      float sum = 0.f;
#pragma unroll
      for (int jj = 0; jj < 3; jj++) { ev[jj] = __expf(ev[jj] - m); sum += ev[jj]; }
      float inv = 1.f / sum;
#pragma unroll
      for (int jj = 0; jj < 3; jj++) {
        float aj = ev[jj] * inv;
        f32x4 xj = *(const f32x4*)&sxf[g_q][blk * 3 + jj][0];
        xa0 += aj * xj[0]; xa1 += aj * xj[1];
        xa2 += aj * xj[2]; xa3 += aj * xj[3];
      }
    } else {
      float ev[9];
      float m = -1e30f;
#pragma unroll
      for (int jj = 0; jj < 9; jj++) {
        int j = jj < blk * 3 ? jj : jj + 3;
        float e = es + sed[g_q][1][h][j];
        e = e > 0.f ? e : 0.2f * e;
        ev[jj] = e;
        m = fmaxf(m, e);
      }
      float sum = 0.f;
#pragma unroll
      for (int jj = 0; jj < 9; jj++) { ev[jj] = __expf(ev[jj] - m); sum += ev[jj]; }
      float inv = 1.f / sum;
#pragma unroll
      for (int jj = 0; jj < 9; jj++) {
        int j = jj < blk * 3 ? jj : jj + 3;
        float aj = ev[jj] * inv;
        f32x4 xj = *(const f32x4*)&sxf[g_q][j][0];
        xa0 += aj * xj[0]; xa1 += aj * xj[1];
        xa2 += aj * xj[2]; xa3 += aj * xj[3];
      }
    }
    uint2 pk = make_uint2(pkbf(xa0, xa1), pkbf(xa2, xa3));
    *(uint2*)&sA[g_q][s_q][i][h * 4] = pk;
  }

  // ---- phase 3 (same wave consumes its own quadrant): wn=w&1, ws=w>>1 ----
  {
    const int wn3 = w & 1, ws3 = w >> 1;
    const short8 z8 = {0,0,0,0,0,0,0,0};
    short8 a = z8;
    if (quad < 2) a = *(const short8*)&sA[wn3][ws3][c15][quad * 8];
#pragma unroll
    for (int tile = 0; tile < 8; tile++) {
      short8 bw = *(const short8*)(fragWB + ((ws3 * 8 + tile) * 64 + lane) * 8);
      f32x4 c = {0.f, 0.f, 0.f, 0.f};
      c = __builtin_amdgcn_mfma_f32_16x16x32_bf16(a, bw, c, 0, 0, 0);
      if (quad < 3) {
        int co = ws3 * 128 + tile * 16 + c15;
        unsigned int p01 = pkbf(eluf(c[0]), eluf(c[1]));
        unsigned int p23 = pkbf(eluf(c[2]), eluf(c[3]));
        scatb[wn3][quad * 4 + 0][co] = (unsigned short)(p01 & 0xffffu);
        scatb[wn3][quad * 4 + 1][co] = (unsigned short)(p01 >> 16);
        scatb[wn3][quad * 4 + 2][co] = (unsigned short)(p23 & 0xffffu);
        scatb[wn3][quad * 4 + 3][co] = (unsigned short)(p23 >> 16);
      }
    }
  }
  __syncthreads();                             // barrier 2 (cross-wave scatb)

  // ---- phase 4: fuse GEMM; wave w covers N-tiles {2w,2w+1}, both nodes ----
  {
    f32x4 acc[2][2];
#pragma unroll
    for (int nd = 0; nd < 2; nd++)
#pragma unroll
      for (int tt = 0; tt < 2; tt++) acc[nd][tt] = (f32x4){0.f,0.f,0.f,0.f};
#pragma unroll
    for (int kb = 0; kb < 8; kb++) {
      short8 a0 = *(const short8*)&scatb[0][c15][kb * 32 + (quad << 3)];
      short8 a1 = *(const short8*)&scatb[1][c15][kb * 32 + (quad << 3)];
#pragma unroll
      for (int tt = 0; tt < 2; tt++) {
        short8 bw = *(const short8*)(fragB + ((kb * 8 + 2 * w + tt) * 64 + lane) * 8);
        acc[0][tt] = __builtin_amdgcn_mfma_f32_16x16x32_bf16(a0, bw, acc[0][tt], 0, 0, 0);
        acc[1][tt] = __builtin_amdgcn_mfma_f32_16x16x32_bf16(a1, bw, acc[1][tt], 0, 0, 0);
      }
    }
    float tot[2][2];
#pragma unroll
    for (int nd = 0; nd < 2; nd++) {
#pragma unroll
      for (int tt = 0; tt < 2; tt++) {
        float p = 0.f;
        if (quad < 3) {
          float bcol = sbias[w * 32 + tt * 16 + c15];
#pragma unroll
          for (int r = 0; r < 4; r++) p += eluf(acc[nd][tt][r] + bcol);
        }
        p += __shfl_xor(p, 16);
        p += __shfl_xor(p, 32);
        tot[nd][tt] = p;
      }
    }
    int ndw = quad >> 1, ttw = quad & 1;
    float val = ndw ? (ttw ? tot[1][1] : tot[1][0])
                    : (ttw ? tot[0][1] : tot[0][0]);
    emb[(n0 + ndw) * 128 + w * 32 + ttw * 16 + c15] = val * (1.f / 12.f);
  }
}

// ---------------------------------------------------------------------------
// Kernel 2: head — r14 structure, 4 barriers. GRU is wave-local (wave 0 = fwd,
// wave 1 = bwd, zero barriers in loop); waves 2-3 concurrently stage
// emb->sCat + f32 passthrough. h written to sCat from registers.
// ---------------------------------------------------------------------------
__global__ __launch_bounds__(256) void head_kernel(
    const float* __restrict__ emb,
    const float* __restrict__ maskp, const float* __restrict__ dirsp,
    const float* __restrict__ W_proj, const float* __restrict__ b_proj,
    const unsigned short* __restrict__ fragP,
    const unsigned short* __restrict__ fragIH,
    const unsigned short* __restrict__ fragHH,
    const float* __restrict__ bih_f, const float* __restrict__ bhh_f,
    const float* __restrict__ bih_b, const float* __restrict__ bhh_b,
    const unsigned short* __restrict__ fragO,
    const float* __restrict__ b_out,
    float* __restrict__ out)
{
  const int b8 = blockIdx.x * 8;
  const int tid = threadIdx.x;
  const int w = tid >> 6, lane = tid & 63, c15 = lane & 15, quad = lane >> 4;

  __shared__ __align__(16) unsigned short sX[32][72];
  __shared__ __align__(16) unsigned short sgi[2][32][96];
  __shared__ float sH[2][8][32];
  __shared__ __align__(16) unsigned short sHb[2][16][32];
  __shared__ float sgh[2][8][96];
  __shared__ __align__(16) unsigned short sCat[16][200];
  __shared__ float sPB[128];
  __shared__ float sBI[2][96], sBH[2][96], sBO[64];

  if (tid < 64) { sPB[tid] = b_proj[tid]; sPB[64 + tid] = W_proj[128 * 64 + tid]; sBO[tid] = b_out[tid]; }
  if (tid < 96) { sBI[0][tid] = bih_f[tid]; sBI[1][tid] = bih_b[tid];
                  sBH[0][tid] = bhh_f[tid]; sBH[1][tid] = bhh_b[tid]; }
  {
    unsigned int* hb = (unsigned int*)sHb;     // 512 dwords
    hb[tid] = 0u; hb[tid + 256] = 0u;
    float* hz = (float*)sH;
    for (int i = tid; i < 512; i += 256) hz[i] = 0.f;
  }
  __syncthreads();                             // B1

  // ---- proj via MFMA ----
  {
    const int mt = w >> 1;
    const int nt0 = (w & 1) * 2;
    const int sloc = mt * 4 + (c15 >> 2);
    const int nbr  = c15 & 3;
    const float* arow = emb + (((b8 + sloc) * 5) + 1 + nbr) * 128;
    short8 a[4];
#pragma unroll
    for (int kb = 0; kb < 4; kb++) {
      const float* p = arow + kb * 32 + quad * 8;
      f32x4 v0 = *(const f32x4*)p;
      f32x4 v1 = *(const f32x4*)(p + 4);
      unsigned short tmp[8];
      tmp[0]=f2b(v0[0]); tmp[1]=f2b(v0[1]); tmp[2]=f2b(v0[2]); tmp[3]=f2b(v0[3]);
      tmp[4]=f2b(v1[0]); tmp[5]=f2b(v1[1]); tmp[6]=f2b(v1[2]); tmp[7]=f2b(v1[3]);
      a[kb] = *(short8*)tmp;
    }
    f32x4 acc0 = {0.f,0.f,0.f,0.f}, acc1 = acc0;
#pragma unroll
    for (int kb = 0; kb < 4; kb++) {
      short8 b0 = *(const short8*)(fragP + ((kb * 4 + nt0    ) * 64 + lane) * 8);
      short8 b1 = *(const short8*)(fragP + ((kb * 4 + nt0 + 1) * 64 + lane) * 8);
      acc0 = __builtin_amdgcn_mfma_f32_16x16x32_bf16(a[kb], b0, acc0, 0, 0, 0);
      acc1 = __builtin_amdgcn_mfma_f32_16x16x32_bf16(a[kb], b1, acc1, 0, 0, 0);
    }
    const int sE = mt * 4 + quad;
    float dirv[4], maskv[4];
#pragma unroll
    for (int r = 0; r < 4; r++) {
      dirv[r]  = dirsp[(b8 + sE) * 4 + r];
      maskv[r] = maskp[(b8 + sE) * 4 + r];
    }
#pragma unroll
    for (int tt = 0; tt < 2; tt++) {
      f32x4 c = tt ? acc1 : acc0;
      int col = (nt0 + tt) * 16 + c15;
#pragma unroll
      for (int r = 0; r < 4; r++) {
        float v = c[r] + dirv[r] * sPB[64 + col] + sPB[col];
        v = fmaxf(v, 0.f) * maskv[r];
        sX[mt * 16 + quad * 4 + r][col] = f2b(v);
      }
    }
  }
  __syncthreads();                             // B2

  // ---- gi via MFMA ----
  {
    const int mt = w >> 1;
    const int ntb = (w & 1) * 3;
    short8 a[2];
#pragma unroll
    for (int kb = 0; kb < 2; kb++)
      a[kb] = *(const short8*)&sX[mt * 16 + c15][kb * 32 + quad * 8];
#pragma unroll
    for (int d = 0; d < 2; d++) {
#pragma unroll
      for (int t2 = 0; t2 < 3; t2++) {
        int nt = ntb + t2;
        f32x4 acc = {0.f,0.f,0.f,0.f};
#pragma unroll
        for (int kb = 0; kb < 2; kb++) {
          short8 bb = *(const short8*)(fragIH + ((d * 12 + kb * 6 + nt) * 64 + lane) * 8);
          acc = __builtin_amdgcn_mfma_f32_16x16x32_bf16(a[kb], bb, acc, 0, 0, 0);
        }
        int col = nt * 16 + c15;
        float bi = sBI[d][col];
#pragma unroll
        for (int r = 0; r < 4; r++)
          sgi[d][mt * 16 + quad * 4 + r][col] = f2b(acc[r] + bi);
      }
    }
  }
  __syncthreads();                             // B3

  if (w < 2) {
    // ---- wave-local GRU: wave w = dir w; zero barriers ----
    const int d = w;
    const int u = lane & 31, sp = lane >> 5;
    for (int step = 0; step < 4; step++) {
      short8 a = *(const short8*)&sHb[d][c15][quad * 8];
#pragma unroll
      for (int nt = 0; nt < 6; nt++) {
        short8 bb = *(const short8*)(fragHH + ((d * 6 + nt) * 64 + lane) * 8);
        f32x4 c = {0.f,0.f,0.f,0.f};
        c = __builtin_amdgcn_mfma_f32_16x16x32_bf16(a, bb, c, 0, 0, 0);
        if (quad < 2) {
          int col = nt * 16 + c15;
#pragma unroll
          for (int r = 0; r < 4; r++) sgh[d][quad * 4 + r][col] = c[r];
        }
      }
      const int k = d ? (3 - step) : step;
#pragma unroll
      for (int si = 0; si < 4; si++) {
        int s = sp + si * 2;
        int row = s * 4 + k;
        float ghr = sgh[d][s][u]      + sBH[d][u];
        float ghz = sgh[d][s][32 + u] + sBH[d][32 + u];
        float ghn = sgh[d][s][64 + u] + sBH[d][64 + u];
        float r = sigm(b2f_u(sgi[d][row][u]) + ghr);
        float z = sigm(b2f_u(sgi[d][row][32 + u]) + ghz);
        float n = tanhf(b2f_u(sgi[d][row][64 + u]) + r * ghn);
        float h = (1.f - z) * n + z * sH[d][s][u];
        sH[d][s][u] = h;
        sHb[d][s][u] = f2b(h);
        if (step == 3) sCat[s][128 + d * 32 + u] = f2b(h);
      }
    }
  } else {
    // ---- waves 2-3: stage self_emb -> sCat cols 0-127 + f32 passthrough ----
    for (int i = tid - 128; i < 1024; i += 128) {
      int s = i >> 7, cc = i & 127;
      float v = emb[(b8 + s) * 5 * 128 + cc];
      sCat[s][cc] = f2b(v);
      out[(b8 + s) * 192 + cc] = v;
    }
  }
  __syncthreads();                             // B4

  // ---- out head via MFMA ----
  {
    const int nt = w;
    f32x4 acc = {0.f,0.f,0.f,0.f};
#pragma unroll
    for (int kb = 0; kb < 6; kb++) {
      short8 a = *(const short8*)&sCat[c15][kb * 32 + quad * 8];
      short8 bb = *(const short8*)(fragO + ((kb * 4 + nt) * 64 + lane) * 8);
      acc = __builtin_amdgcn_mfma_f32_16x16x32_bf16(a, bb, acc, 0, 0, 0);
    }
    if (quad < 2) {
      int col = nt * 16 + c15;
#pragma unroll
      for (int r = 0; r < 4; r++) {
        int m = quad * 4 + r;
        out[(b8 + m) * 192 + 128 + col] = fmaxf(acc[r] + sBO[col], 0.f);
      }
    }
  }
}

// ---------------------------------------------------------------------------
extern "C" void kernel_launch(void* const* d_in, const int* in_sizes, int n_in,
                              void* d_out, int out_size, void* d_ws, size_t ws_size,
                              hipStream_t stream) {
  const float* self_f  = (const float*)d_in[0];
  const float* nbr_f   = (const float*)d_in[1];
  const float* maskp   = (const float*)d_in[2];
  const float* dirsp   = (const float*)d_in[3];
  const float* W_coop  = (const float*)d_in[4];
  const float* as_coop = (const float*)d_in[5];
  const float* ad_coop = (const float*)d_in[6];
  const float* W_conf  = (const float*)d_in[7];
  const float* as_conf = (const float*)d_in[8];
  const float* ad_conf = (const float*)d_in[9];
  const float* W_fuse  = (const float*)d_in[10];
  const float* b_fuse  = (const float*)d_in[11];
  const float* W_proj  = (const float*)d_in[12];
  const float* b_proj  = (const float*)d_in[13];
  const float* Wih_f   = (const float*)d_in[14];
  const float* Whh_f   = (const float*)d_in[15];
  const float* bih_f   = (const float*)d_in[16];
  const float* bhh_f   = (const float*)d_in[17];
  const float* Wih_b   = (const float*)d_in[18];
  const float* Whh_b   = (const float*)d_in[19];
  const float* bih_b   = (const float*)d_in[20];
  const float* bhh_b   = (const float*)d_in[21];
  const float* W_out   = (const float*)d_in[22];
  const float* b_out   = (const float*)d_in[23];

  const int B = in_sizes[0] / 48;   // 8192
  char* ws = (char*)d_ws;
  unsigned short* fragB  = (unsigned short*)(ws);            // 65536 B
  unsigned short* fragWB = (unsigned short*)(ws + 65536);    // 16384 B
  float*          Wa     = (float*)(ws + 81920);             // 256 B
  unsigned short* fragP  = (unsigned short*)(ws + 82176);    // 16384 B
  unsigned short* fragIH = (unsigned short*)(ws + 98560);    // 24576 B
  unsigned short* fragO  = (unsigned short*)(ws + 123136);   // 24576 B
  unsigned short* fragHH = (unsigned short*)(ws + 147712);   // 12288 B
  float*          emb    = (float*)(ws + 160000);            // B*5*128*4

  prepack_kernel<<<40, 256, 0, stream>>>(
      W_fuse, W_coop, W_conf, as_coop, ad_coop, as_conf, ad_conf,
      W_proj, Wih_f, Wih_b, W_out, Whh_f, Whh_b,
      fragB, fragWB, Wa, fragP, fragIH, fragO, fragHH);

  gat_fuse_kernel<<<B * 5 / 2, 256, 0, stream>>>(
      self_f, nbr_f, Wa, fragWB, fragB, b_fuse, emb);

  head_kernel<<<B / 8, 256, 0, stream>>>(
      emb, maskp, dirsp, W_proj, b_proj, fragP, fragIH, fragHH,
      bih_f, bhh_f, bih_b, bhh_b,
      fragO, b_out, (float*)d_out);
}